// Round 2
// 265.515 us; speedup vs baseline: 1.1292x; 1.1292x over previous
//
#include <hip/hip_runtime.h>

// MultiHeadAttention with memory tokens + residual + LayerNorm.
// Inputs f32 (mask int32), OUTPUT f32.  B=4, N=1024, D=1024, H=16, DK=64,
// M=64, NKV=1088.  Intermediates bf16 (MFMA), f32 accumulation.
//
// R11 == R10 resubmit (R10 bench was an infra failure, no counters).
// R10: pre-convert A and W to bf16 (cvt_bf16), then m97-style GEMM with
// global_load_lds width-16 direct staging (linear LDS, no pad), DMA of the
// next K-tile overlapped with the 16 MFMAs.  Old f32-staged gemm128 kept as
// workspace-size fallback.

typedef __bf16 bf16;
typedef __bf16 bf16x8 __attribute__((ext_vector_type(8)));
typedef __bf16 bf16x4 __attribute__((ext_vector_type(4)));
typedef float  f32x4  __attribute__((ext_vector_type(4)));

#define NSEQ 1024
#define NKV  1088
#define DMODEL 1024

// ---------------------------------------------------------------------------
// f32 -> bf16 conversion of all GEMM operands into one contiguous dst:
// [queries 4Mi][keys 4Mi][values 4Mi][Wq 1Mi][Wk 1Mi][Wv 1Mi][Wo 1Mi] elems.
struct CvtArgs { const float* s[7]; };

__global__ __launch_bounds__(256) void cvt_bf16(CvtArgs c, bf16* __restrict__ dst)
{
    size_t e = ((size_t)blockIdx.x * 256 + threadIdx.x) * 8;
    const float* s;
    if (e < ((size_t)3 << 22)) {
        s = c.s[e >> 22] + (e & 0x3FFFFF);
    } else {
        size_t wq = e - ((size_t)3 << 22);
        s = c.s[3 + (wq >> 20)] + (wq & 0xFFFFF);
    }
    f32x4 a = *(const f32x4*)s;
    f32x4 b = *(const f32x4*)(s + 4);
    bf16x8 o;
    for (int i = 0; i < 4; i++) { o[i] = (bf16)a[i]; o[4 + i] = (bf16)b[i]; }
    *(bf16x8*)&dst[e] = o;
}

// ---------------------------------------------------------------------------
// async global->LDS, 16 B per lane (wave-uniform LDS base + lane*16 in HW)
typedef __attribute__((address_space(1))) void gas_void;
typedef __attribute__((address_space(3))) void las_void;

__device__ __forceinline__ void gload16(const bf16* g, bf16* l)
{
    __builtin_amdgcn_global_load_lds((gas_void*)g, (las_void*)l, 16, 0, 0);
}

struct GemmArgsB {
    const bf16* A;        // [M][1024] bf16
    const bf16* W;        // [1024][1024] bf16
    const float* bias;    // [1024] f32
    bf16* C;
    int osK;              // batch stride for multi-batch row remap (vt=0)
    int vt;               // 1: V-transposed epilogue
};

// C = A @ W.T + bias.  128x128 tile, BK=32, 4 waves (2x2), 4x4 16x16 frags.
// Staging: global_load_lds dwordx4 into linear LDS [128][32] (m97 structure).
// grid (N/128, M/128, nz).
__global__ __launch_bounds__(256, 3) void gemm128_lds(GemmArgsB g0, GemmArgsB g1,
                                                      GemmArgsB g2)
{
    const GemmArgsB g = (blockIdx.z == 0) ? g0 : (blockIdx.z == 1) ? g1 : g2;
    __shared__ bf16 As[128][32];
    __shared__ bf16 Bs[128][32];
    const int t = threadIdx.x;
    const int lane = t & 63, w = t >> 6;
    const int qi = lane & 15, qq = lane >> 4;
    const int wrow = (w >> 1) * 64, wcol = (w & 1) * 64;
    const int bm = blockIdx.y * 128, bn = blockIdx.x * 128;

    // wave w stages rows [w*32, w*32+32) of A and B: two 1 KB DMAs each.
    // lane l covers row w*32 + (l>>2), elems (l&3)*8 .. +8  (linear LDS req.)
    const int srow = w * 32 + (lane >> 2);
    const int scol = (lane & 3) * 8;
    const bf16* Ag = g.A + (size_t)(bm + srow) * DMODEL + scol;
    const bf16* Wg = g.W + (size_t)(bn + srow) * DMODEL + scol;
    bf16* Al = &As[w * 32][0];
    bf16* Bl = &Bs[w * 32][0];

    f32x4 acc[4][4] = {};

#define STAGE(kt)                                                             \
    do {                                                                      \
        gload16(Ag + (kt),                 Al);                               \
        gload16(Ag + (kt) + 16 * DMODEL,   Al + 16 * 32);                     \
        gload16(Wg + (kt),                 Bl);                               \
        gload16(Wg + (kt) + 16 * DMODEL,   Bl + 16 * 32);                     \
    } while (0)

    STAGE(0);
    for (int kt = 0; kt < DMODEL; kt += 32) {
        __syncthreads();                       // DMA for tile kt complete
        bf16x8 a[4], b[4];
        for (int i = 0; i < 4; i++)
            a[i] = *(const bf16x8*)&As[wrow + i * 16 + qi][qq * 8];
        for (int j = 0; j < 4; j++)
            b[j] = *(const bf16x8*)&Bs[wcol + j * 16 + qi][qq * 8];
        __syncthreads();                       // all waves done reading LDS
        if (kt + 32 < DMODEL) STAGE(kt + 32);  // DMA overlaps MFMAs below
        for (int i = 0; i < 4; i++)
            for (int j = 0; j < 4; j++)
                acc[i][j] = __builtin_amdgcn_mfma_f32_16x16x32_bf16(
                    a[i], b[j], acc[i][j], 0, 0, 0);
    }
#undef STAGE

    // epilogue; C/D layout row=qq*4+r, col=qi  [m89-verified]
    for (int i = 0; i < 4; i++)
        for (int j = 0; j < 4; j++) {
            int row0 = bm + wrow + i * 16 + qq * 4;
            int col  = bn + wcol + j * 16 + qi;
            float bcol = g.bias[col];
            if (g.vt) {
                bf16x4 v;
                for (int r = 0; r < 4; r++) v[r] = (bf16)(acc[i][j][r] + bcol);
                size_t off = ((size_t)((row0 >> 10) * 16 + (col >> 6)) * 64 + (col & 63))
                           * NKV + (row0 & 1023);
                *(bf16x4*)&g.C[off] = v;
            } else {
                for (int r = 0; r < 4; r++) {
                    int row = row0 + r;
                    size_t off = (size_t)(row >> 10) * g.osK
                               + (size_t)(row & 1023) * DMODEL + col;
                    g.C[off] = (bf16)(acc[i][j][r] + bcol);
                }
            }
        }
}

// ---------------------------------------------------------------------------
// Old f32-staged GEMM — kept for small-workspace fallback paths.
struct GemmArgs {
    const void* A;        // [M][1024] f32 (or bf16 if ABF)
    const float* W;       // [1024][1024] f32
    const float* bias;    // [1024] f32
    bf16* C;
    int osK;
    int vt;
};

template<bool ABF>
__global__ __launch_bounds__(256, 2) void gemm128(GemmArgs g0, GemmArgs g1, GemmArgs g2)
{
    const GemmArgs g = (blockIdx.z == 0) ? g0 : (blockIdx.z == 1) ? g1 : g2;
    __shared__ bf16 As[128][44];
    __shared__ bf16 Bs[128][44];
    const int t = threadIdx.x;
    const int lane = t & 63, w = t >> 6;
    const int qi = lane & 15, qq = lane >> 4;
    const int wrow = (w >> 1) * 64, wcol = (w & 1) * 64;
    const int bm = blockIdx.y * 128, bn = blockIdx.x * 128;
    const int sr = t >> 1, sc = (t & 1) * 16;

    f32x4 acc[4][4] = {};

    f32x4 pa[4];
    bf16x8 pab[2];
    f32x4 pw[4];

    const float* Wp = g.W + (size_t)(bn + sr) * DMODEL + sc;
    const float* Af = (const float*)g.A + (size_t)(bm + sr) * DMODEL + sc;
    const bf16*  Ab = (const bf16*)g.A + (size_t)(bm + sr) * DMODEL + sc;

#define LOAD_TILES(kt)                                                        \
    do {                                                                      \
        if (ABF) {                                                            \
            pab[0] = *(const bf16x8*)(Ab + (kt));                             \
            pab[1] = *(const bf16x8*)(Ab + (kt) + 8);                         \
        } else {                                                              \
            pa[0] = *(const f32x4*)(Af + (kt));                               \
            pa[1] = *(const f32x4*)(Af + (kt) + 4);                           \
            pa[2] = *(const f32x4*)(Af + (kt) + 8);                           \
            pa[3] = *(const f32x4*)(Af + (kt) + 12);                          \
        }                                                                     \
        pw[0] = *(const f32x4*)(Wp + (kt));                                   \
        pw[1] = *(const f32x4*)(Wp + (kt) + 4);                               \
        pw[2] = *(const f32x4*)(Wp + (kt) + 8);                               \
        pw[3] = *(const f32x4*)(Wp + (kt) + 12);                              \
    } while (0)

#define STORE_TILES()                                                         \
    do {                                                                      \
        if (ABF) {                                                            \
            *(bf16x8*)&As[sr][sc]     = pab[0];                               \
            *(bf16x8*)&As[sr][sc + 8] = pab[1];                               \
        } else {                                                              \
            bf16x8 v0, v1;                                                    \
            for (int i = 0; i < 4; i++) {                                     \
                v0[i] = (bf16)pa[0][i]; v0[4 + i] = (bf16)pa[1][i];           \
                v1[i] = (bf16)pa[2][i]; v1[4 + i] = (bf16)pa[3][i];           \
            }                                                                 \
            *(bf16x8*)&As[sr][sc]     = v0;                                   \
            *(bf16x8*)&As[sr][sc + 8] = v1;                                   \
        }                                                                     \
        {                                                                     \
            bf16x8 u0, u1;                                                    \
            for (int i = 0; i < 4; i++) {                                     \
                u0[i] = (bf16)pw[0][i]; u0[4 + i] = (bf16)pw[1][i];           \
                u1[i] = (bf16)pw[2][i]; u1[4 + i] = (bf16)pw[3][i];           \
            }                                                                 \
            *(bf16x8*)&Bs[sr][sc]     = u0;                                   \
            *(bf16x8*)&Bs[sr][sc + 8] = u1;                                   \
        }                                                                     \
    } while (0)

    LOAD_TILES(0);
    STORE_TILES();
    __syncthreads();

    for (int kt = 0; kt < DMODEL; kt += 32) {
        const bool more = (kt + 32) < DMODEL;
        if (more) LOAD_TILES(kt + 32);
        bf16x8 a[4], b[4];
        for (int i = 0; i < 4; i++)
            a[i] = *(const bf16x8*)&As[wrow + i * 16 + qi][qq * 8];
        for (int j = 0; j < 4; j++)
            b[j] = *(const bf16x8*)&Bs[wcol + j * 16 + qi][qq * 8];
        for (int i = 0; i < 4; i++)
            for (int j = 0; j < 4; j++)
                acc[i][j] = __builtin_amdgcn_mfma_f32_16x16x32_bf16(a[i], b[j], acc[i][j], 0, 0, 0);
        if (more) {
            __syncthreads();
            STORE_TILES();
            __syncthreads();
        }
    }
#undef LOAD_TILES
#undef STORE_TILES

    for (int i = 0; i < 4; i++)
        for (int j = 0; j < 4; j++) {
            int row0 = bm + wrow + i * 16 + qq * 4;
            int col  = bn + wcol + j * 16 + qi;
            float bcol = g.bias[col];
            if (g.vt) {
                bf16x4 v;
                for (int r = 0; r < 4; r++) v[r] = (bf16)(acc[i][j][r] + bcol);
                size_t off = ((size_t)((row0 >> 10) * 16 + (col >> 6)) * 64 + (col & 63))
                           * NKV + (row0 & 1023);
                *(bf16x4*)&g.C[off] = v;
            } else {
                for (int r = 0; r < 4; r++) {
                    int row = row0 + r;
                    size_t off = (size_t)(row >> 10) * g.osK
                               + (size_t)(row & 1023) * DMODEL + col;
                    g.C[off] = (bf16)(acc[i][j][r] + bcol);
                }
            }
        }
}

// ---------------------------------------------------------------------------
__global__ void fill_mem(const float* __restrict__ mk, const float* __restrict__ mv,
                         bf16* __restrict__ K, bf16* __restrict__ Vt)
{
    int i = blockIdx.x * 256 + threadIdx.x;
    int b = i >> 16, md = i & 65535;
    int m = md >> 10, dcol = md & 1023;
    K[(size_t)b * (NKV * DMODEL) + (size_t)(NSEQ + m) * DMODEL + dcol]
        = (bf16)(mk[md] * 8.0f);
    Vt[((size_t)b * 1024 + dcol) * NKV + NSEQ + m] = (bf16)(mv[md] * 8.0f);
}

// ---------------------------------------------------------------------------
// Flash attention with register-dbuf K/V prefetch.  grid (NSEQ/64, nb*16).
__global__ __launch_bounds__(256) void attn_flash(const bf16* Q,
        const bf16* __restrict__ K, const bf16* __restrict__ Vt,
        const int* __restrict__ mask, bf16* O)
{
    __shared__ bf16  sK[64][72];
    __shared__ bf16  sV[64][72];
    __shared__ bf16  sP[4][16][72];
    __shared__ float sM[NKV];
    const int t = threadIdx.x, lane = t & 63, w = t >> 6;
    const int bh = blockIdx.y, b = bh >> 4, h = bh & 15;
    const int q0 = blockIdx.x * 64;
    const int sr = t >> 2, sc = (t & 3) * 16;
    const int qi = lane & 15, qq = lane >> 4;

    for (int j = t; j < NKV; j += 256)
        sM[j] = (j < NSEQ && mask[b * NSEQ + j] != 0) ? -3.0e38f : 0.0f;

    const size_t qbase = (size_t)(b * NSEQ + q0 + w * 16 + qi) * DMODEL
                       + h * 64 + qq * 8;
    bf16x8 qa0 = *(const bf16x8*)&Q[qbase];
    bf16x8 qa1 = *(const bf16x8*)&Q[qbase + 32];
    for (int i = 0; i < 8; i++) {
        qa0[i] = (bf16)((float)qa0[i] * 0.125f);
        qa1[i] = (bf16)((float)qa1[i] * 0.125f);
    }

    const bf16* kbase = K + (size_t)(b * NKV + sr) * DMODEL + h * 64 + sc;
    const bf16* vbase = Vt + ((size_t)bh * 64 + sr) * NKV + sc;

    bf16x8 pk0, pk1, pv0, pv1;
#define LOAD_KV(jt)                                                           \
    do {                                                                      \
        const bf16* kp = kbase + (size_t)(jt) * 64 * DMODEL;                  \
        pk0 = *(const bf16x8*)kp;                                             \
        pk1 = *(const bf16x8*)(kp + 8);                                       \
        const bf16* vp = vbase + (jt) * 64;                                   \
        pv0 = *(const bf16x8*)vp;                                             \
        pv1 = *(const bf16x8*)(vp + 8);                                       \
    } while (0)
#define STORE_KV()                                                            \
    do {                                                                      \
        *(bf16x8*)&sK[sr][sc]     = pk0;                                      \
        *(bf16x8*)&sK[sr][sc + 8] = pk1;                                      \
        *(bf16x8*)&sV[sr][sc]     = pv0;                                      \
        *(bf16x8*)&sV[sr][sc + 8] = pv1;                                      \
    } while (0)

    LOAD_KV(0);
    STORE_KV();

    float m_i[4], l_i[4];
    f32x4 oacc[4] = {};
    for (int r = 0; r < 4; r++) { m_i[r] = -3.0e38f; l_i[r] = 0.f; }

    for (int jt = 0; jt < 17; jt++) {
        const int j0 = jt * 64;
        __syncthreads();
        const bool more = jt < 16;
        if (more) LOAD_KV(jt + 1);

        f32x4 s[4];
        for (int g = 0; g < 4; g++) {
            bf16x8 b0 = *(const bf16x8*)&sK[g * 16 + qi][qq * 8];
            bf16x8 b1 = *(const bf16x8*)&sK[g * 16 + qi][32 + qq * 8];
            f32x4 a = {};
            a = __builtin_amdgcn_mfma_f32_16x16x32_bf16(qa0, b0, a, 0, 0, 0);
            a = __builtin_amdgcn_mfma_f32_16x16x32_bf16(qa1, b1, a, 0, 0, 0);
            float msk = sM[j0 + g * 16 + qi];
            for (int r = 0; r < 4; r++) s[g][r] = a[r] + msk;
        }
        float alpha[4];
        for (int r = 0; r < 4; r++) {
            float rm = fmaxf(fmaxf(s[0][r], s[1][r]), fmaxf(s[2][r], s[3][r]));
            for (int o = 1; o < 16; o <<= 1) rm = fmaxf(rm, __shfl_xor(rm, o, 64));
            float mnew = fmaxf(m_i[r], rm);
            alpha[r] = __expf(m_i[r] - mnew);
            m_i[r] = mnew;
            float rs = 0.f;
            for (int g = 0; g < 4; g++) {
                float p = __expf(s[g][r] - mnew);
                s[g][r] = p;
                rs += p;
            }
            for (int o = 1; o < 16; o <<= 1) rs += __shfl_xor(rs, o, 64);
            l_i[r] = l_i[r] * alpha[r] + rs;
        }
        for (int g = 0; g < 4; g++)
            for (int r = 0; r < 4; r++) {
                sP[w][qq * 4 + r][g * 16 + qi] = (bf16)s[g][r];
                oacc[g][r] *= alpha[r];
            }
        bf16x8 af0 = *(const bf16x8*)&sP[w][qi][qq * 8];
        bf16x8 af1 = *(const bf16x8*)&sP[w][qi][32 + qq * 8];
        for (int g = 0; g < 4; g++) {
            bf16x8 v0 = *(const bf16x8*)&sV[g * 16 + qi][qq * 8];
            bf16x8 v1 = *(const bf16x8*)&sV[g * 16 + qi][32 + qq * 8];
            oacc[g] = __builtin_amdgcn_mfma_f32_16x16x32_bf16(af0, v0, oacc[g], 0, 0, 0);
            oacc[g] = __builtin_amdgcn_mfma_f32_16x16x32_bf16(af1, v1, oacc[g], 0, 0, 0);
        }
        __syncthreads();
        if (more) STORE_KV();
    }
#undef LOAD_KV
#undef STORE_KV

    float inv[4];
    for (int r = 0; r < 4; r++) inv[r] = 1.0f / l_i[r];
    for (int g = 0; g < 4; g++)
        for (int r = 0; r < 4; r++) {
            int row = q0 + w * 16 + qq * 4 + r;
            int col = h * 64 + g * 16 + qi;
            O[(size_t)(b * NSEQ + row) * DMODEL + col] = (bf16)(oacc[g][r] * inv[r]);
        }
}

// ---------------------------------------------------------------------------
__global__ __launch_bounds__(256) void residual_ln(const float* __restrict__ X,
        const bf16* __restrict__ Y, const float* __restrict__ gamma,
        const float* __restrict__ beta, float* __restrict__ out)
{
    __shared__ float red[8];
    int row = blockIdx.x, t = threadIdx.x;
    size_t base = (size_t)row * DMODEL + t * 4;
    f32x4  xv = *(const f32x4*)&X[base];
    bf16x4 yv = *(const bf16x4*)&Y[base];
    float s[4], sum = 0.f, sq = 0.f;
    for (int i = 0; i < 4; i++) {
        s[i] = xv[i] + (float)yv[i];
        sum += s[i]; sq += s[i] * s[i];
    }
    for (int o = 32; o; o >>= 1) { sum += __shfl_xor(sum, o, 64); sq += __shfl_xor(sq, o, 64); }
    if ((t & 63) == 0) { red[t >> 6] = sum; red[4 + (t >> 6)] = sq; }
    __syncthreads();
    sum = red[0] + red[1] + red[2] + red[3];
    sq  = red[4] + red[5] + red[6] + red[7];
    float mean = sum * (1.0f / DMODEL);
    float var  = sq  * (1.0f / DMODEL) - mean * mean;
    float rstd = rsqrtf(var + 1e-5f);
    f32x4 gv = *(const f32x4*)&gamma[t * 4];
    f32x4 bv = *(const f32x4*)&beta[t * 4];
    f32x4 ov;
    for (int i = 0; i < 4; i++)
        ov[i] = (s[i] - mean) * rstd * gv[i] + bv[i];
    *(f32x4*)&out[base] = ov;
}

// ---------------------------------------------------------------------------
extern "C" void kernel_launch(void* const* d_in, const int* in_sizes, int n_in,
                              void* d_out, int out_size, void* d_ws, size_t ws_size,
                              hipStream_t stream)
{
    const float* queries = (const float*)d_in[0];
    const float* keys    = (const float*)d_in[1];
    const float* values  = (const float*)d_in[2];
    const int*   amask   = (const int*)d_in[3];
    const float* Wq = (const float*)d_in[4];  const float* bq = (const float*)d_in[5];
    const float* Wk = (const float*)d_in[6];  const float* bk = (const float*)d_in[7];
    const float* Wv = (const float*)d_in[8];  const float* bv = (const float*)d_in[9];
    const float* Wo = (const float*)d_in[10]; const float* bo = (const float*)d_in[11];
    const float* mk = (const float*)d_in[12]; const float* mv = (const float*)d_in[13];
    const float* gamma = (const float*)d_in[14]; const float* beta = (const float*)d_in[15];
    float* out = (float*)d_out;

    bf16* Qb = (bf16*)(out + (size_t)2 * 1024 * 1024);   // d_out upper 8 MB
    const size_t SB  = (size_t)NSEQ * DMODEL;            // 1,048,576 elems
    const size_t KVB = (size_t)NKV * DMODEL;             // 1,114,112 elems
    dim3 gb(256);

    // R10 path needs Kb + Vt + Ab(q,k,v bf16) + Wb(4 matrices bf16):
    const size_t need_r10 = (2 * 4 * KVB + 3 * 4 * SB + 4 * SB) * sizeof(bf16);

    if (ws_size >= need_r10) {
        // ---------- bf16 + global_load_lds path (ws >= ~49 MB) ----------
        bf16* Kb = (bf16*)d_ws;            // [4][1088][1024]
        bf16* Vt = Kb + 4 * KVB;           // [4*16*64][1088]
        bf16* Ab = Vt + 4 * KVB;           // [3][4][1024][1024] bf16 (q,k,v)
        bf16* Wb = Ab + 12 * SB;           // [4][1024][1024] bf16 (Wq,Wk,Wv,Wo)
        bf16* PR = Ab;                     // gemm-o output aliases dead Ab

        CvtArgs ca;
        ca.s[0] = queries; ca.s[1] = keys; ca.s[2] = values;
        ca.s[3] = Wq; ca.s[4] = Wk; ca.s[5] = Wv; ca.s[6] = Wo;
        cvt_bf16<<<dim3(8192), gb, 0, stream>>>(ca, Ab);

        GemmArgsB gq{Ab,           Wb,           bq, Qb, (int)SB,  0};
        GemmArgsB gk{Ab + 4 * SB,  Wb + SB,      bk, Kb, (int)KVB, 0};
        GemmArgsB gv{Ab + 8 * SB,  Wb + 2 * SB,  bv, Vt, 0,        1};
        gemm128_lds<<<dim3(8, 32, 3), gb, 0, stream>>>(gq, gk, gv);
        fill_mem<<<dim3(1024), gb, 0, stream>>>(mk, mv, Kb, Vt);
        attn_flash<<<dim3(16, 64), gb, 0, stream>>>(Qb, Kb, Vt, amask, Qb);
        GemmArgsB go{Qb, Wb + 3 * SB, bo, PR, (int)SB, 0};
        gemm128_lds<<<dim3(8, 32, 1), gb, 0, stream>>>(go, go, go);
        residual_ln<<<dim3(4096), gb, 0, stream>>>(queries, PR, gamma, beta, out);
    } else if (ws_size >= (size_t)2 * 4 * KVB * sizeof(bf16)) {
        // ---------- batched f32-staged fallback (ws >= 17,825,792 B) ----------
        bf16* Kb = (bf16*)d_ws;            // [4][1088][1024]
        bf16* Vt = Kb + 4 * KVB;           // [4*16*64][1088]
        bf16* PR = Kb;                     // [4096][1024] aliases dead Kb

        GemmArgs gq{queries, Wq, bq, Qb, (int)SB,  0};
        GemmArgs gk{keys,    Wk, bk, Kb, (int)KVB, 0};
        GemmArgs gv{values,  Wv, bv, Vt, 0,        1};
        gemm128<false><<<dim3(8, 32, 3), gb, 0, stream>>>(gq, gk, gv);
        fill_mem<<<dim3(1024), gb, 0, stream>>>(mk, mv, Kb, Vt);
        attn_flash<<<dim3(16, 64), gb, 0, stream>>>(Qb, Kb, Vt, amask, Qb);
        GemmArgs go{Qb, Wo, bo, PR, (int)SB, 0};
        gemm128<true><<<dim3(8, 32, 1), gb, 0, stream>>>(go, go, go);
        residual_ln<<<dim3(4096), gb, 0, stream>>>(queries, PR, gamma, beta, out);
    } else {
        // ---------- per-batch fallback (ws >= 4,456,448 B) ----------
        bf16* Kb = (bf16*)d_ws;            // [1088][1024]
        bf16* Vt = Kb + KVB;               // [16*64][1088]
        bf16* PR = Kb;

        GemmArgs gq{queries, Wq, bq, Qb, (int)SB, 0};
        gemm128<false><<<dim3(8, 32, 1), gb, 0, stream>>>(gq, gq, gq);
        for (int b = 0; b < 4; b++) {
            GemmArgs gk{keys   + b * SB, Wk, bk, Kb, 0, 0};
            GemmArgs gv{values + b * SB, Wv, bv, Vt, 0, 1};
            gemm128<false><<<dim3(8, 8, 2), gb, 0, stream>>>(gk, gv, gv);
            fill_mem<<<dim3(256), gb, 0, stream>>>(mk, mv, Kb, Vt);
            attn_flash<<<dim3(16, 16), gb, 0, stream>>>(Qb + b * SB, Kb, Vt,
                                                        amask + b * NSEQ, Qb + b * SB);
            GemmArgs go{Qb + b * SB, Wo, bo, PR, 0, 0};
            gemm128<true><<<dim3(8, 8, 1), gb, 0, stream>>>(go, go, go);
            residual_ln<<<dim3(1024), gb, 0, stream>>>(queries + b * SB, PR,
                                                       gamma, beta, out + b * SB);
        }
    }
}